// Round 1
// baseline (230.887 us; speedup 1.0000x reference)
//
#include <hip/hip_runtime.h>
#include <hip/hip_bf16.h>

// Problem constants
#define S_LEN   4096
#define D_MOD   512
#define BATCH   4
#define HALF_W  128
#define M_TOT   (BATCH * S_LEN)   // 16384

typedef __attribute__((ext_vector_type(8))) short bf16x8;
typedef __attribute__((ext_vector_type(4))) float f32x4;

__device__ __forceinline__ unsigned short f2bf(float f) {
    // round-to-nearest-even bf16 (values are finite here)
    unsigned int u = __float_as_uint(f);
    unsigned int r = (u + 0x7fffu + ((u >> 16) & 1u)) >> 16;
    return (unsigned short)r;
}

__device__ __forceinline__ void async_copy16(const void* g, void* l) {
    __builtin_amdgcn_global_load_lds(
        (const __attribute__((address_space(1))) void*)g,
        (__attribute__((address_space(3))) void*)l, 16, 0, 0);
}

// ---------------------------------------------------------------------------
// Kernel 1: x fp32 -> bf16 (row-major [16384][512])
__global__ __launch_bounds__(256) void convert_x(const float* __restrict__ x,
                                                 unsigned short* __restrict__ xb) {
    int i = (blockIdx.x * 256 + threadIdx.x) * 4;
    float4 v = *(const float4*)(x + i);
    ushort4 o;
    o.x = f2bf(v.x); o.y = f2bf(v.y); o.z = f2bf(v.z); o.w = f2bf(v.w);
    *(ushort4*)(xb + i) = o;
}

// Kernel 2: W[k][n] fp32 -> Wt[n][k] bf16 for the 3 weights (B-operand wants k contiguous)
__global__ __launch_bounds__(256) void convert_w(const float* __restrict__ Wq,
                                                 const float* __restrict__ Wk,
                                                 const float* __restrict__ Wv,
                                                 unsigned short* __restrict__ Wt) {
    int idx = blockIdx.x * 256 + threadIdx.x;          // 3*512*512 total
    int w = idx >> 18;
    int rem = idx & 262143;
    int k = rem >> 9;
    int n = rem & 511;
    const float* W = (w == 0) ? Wq : ((w == 1) ? Wk : Wv);
    Wt[w * 262144 + n * 512 + k] = f2bf(W[k * 512 + n]);
}

// ---------------------------------------------------------------------------
// Kernel 3: fused QKV GEMM.  out[m][n] = sum_k xb[m][k] * W[k][n] + b[n]
// 128x128 tile, BK=64, 16x16x32 bf16 MFMA, global_load_lds staging.
// z=0 -> Q row-major, z=1 -> K row-major, z=2 -> V stored TRANSPOSED Vt[n][m].
__global__ __launch_bounds__(256) void qkv_gemm(
    const unsigned short* __restrict__ xb, const unsigned short* __restrict__ Wt,
    const float* __restrict__ bq, const float* __restrict__ bk, const float* __restrict__ bv,
    unsigned short* __restrict__ Qo, unsigned short* __restrict__ Ko,
    unsigned short* __restrict__ Vt) {
    __shared__ __align__(16) unsigned short sA[128 * 64];
    __shared__ __align__(16) unsigned short sB[128 * 64];

    const int t = threadIdx.x;
    const int m0 = blockIdx.x * 128;
    const int n0 = blockIdx.y * 128;
    const int wsel = blockIdx.z;
    const unsigned short* Wb = Wt + wsel * 262144;

    const int w = t >> 6, lane = t & 63;
    const int wm = (w & 1) * 64, wn = (w >> 1) * 64;
    const int qd = lane >> 4, l16 = lane & 15;

    f32x4 acc[4][4] = {};

    for (int k0 = 0; k0 < 512; k0 += 64) {
        __syncthreads();
        #pragma unroll
        for (int i = 0; i < 4; ++i) {
            int c = i * 256 + t;
            int row = c >> 3, cc = c & 7;
            async_copy16(xb + (m0 + row) * 512 + k0 + cc * 8, sA + c * 8);
            async_copy16(Wb + (n0 + row) * 512 + k0 + cc * 8, sB + c * 8);
        }
        __syncthreads();
        #pragma unroll
        for (int ks = 0; ks < 2; ++ks) {
            bf16x8 af[4], bfr[4];
            #pragma unroll
            for (int i = 0; i < 4; ++i)
                af[i] = *(const bf16x8*)(sA + (wm + i * 16 + l16) * 64 + ks * 32 + qd * 8);
            #pragma unroll
            for (int j = 0; j < 4; ++j)
                bfr[j] = *(const bf16x8*)(sB + (wn + j * 16 + l16) * 64 + ks * 32 + qd * 8);
            #pragma unroll
            for (int i = 0; i < 4; ++i)
                #pragma unroll
                for (int j = 0; j < 4; ++j)
                    acc[i][j] = __builtin_amdgcn_mfma_f32_16x16x32_bf16(af[i], bfr[j], acc[i][j], 0, 0, 0);
        }
    }

    const float* bias = (wsel == 0) ? bq : ((wsel == 1) ? bk : bv);
    if (wsel < 2) {
        unsigned short* Og = (wsel == 0) ? Qo : Ko;
        #pragma unroll
        for (int j = 0; j < 4; ++j) {
            int n = n0 + wn + j * 16 + l16;
            float bj = bias[n];
            #pragma unroll
            for (int i = 0; i < 4; ++i) {
                int mb = m0 + wm + i * 16 + qd * 4;
                #pragma unroll
                for (int r = 0; r < 4; ++r)
                    Og[(mb + r) * 512 + n] = f2bf(acc[i][j][r] + bj);
            }
        }
    } else {
        #pragma unroll
        for (int j = 0; j < 4; ++j) {
            int n = n0 + wn + j * 16 + l16;
            float bj = bias[n];
            #pragma unroll
            for (int i = 0; i < 4; ++i) {
                int mb = m0 + wm + i * 16 + qd * 4;
                #pragma unroll
                for (int r = 0; r < 4; ++r)
                    Vt[n * M_TOT + mb + r] = f2bf(acc[i][j][r] + bj);
            }
        }
    }
}

// ---------------------------------------------------------------------------
// Kernel 4: banded attention. Block = 32 queries, 9 key-tiles of 32.
// No-max single-pass softmax (scores ~N(0,1); overflow impossible).
__global__ __launch_bounds__(256) void attn(const unsigned short* __restrict__ Qg,
                                            const unsigned short* __restrict__ Kg,
                                            const unsigned short* __restrict__ Vt,
                                            float* __restrict__ out) {
    __shared__ __align__(16) unsigned short sQ[32 * 512];   // 32 KB
    __shared__ __align__(16) unsigned short sK[32 * 128];   // 8 KB (D chunk)
    __shared__ __align__(16) unsigned short sV[128 * 32];   // 8 KB (D chunk, transposed layout)
    __shared__ __align__(16) unsigned short sP[32 * 32];    // 2 KB
    __shared__ float lsum[32];

    const int t = threadIdx.x;
    const int q0 = blockIdx.x * 32;      // query offset within batch
    const int b = blockIdx.y;
    const int bS = b * S_LEN;
    const int w = t >> 6, lane = t & 63;
    const int qd = lane >> 4, l16 = lane & 15;
    const int qh = (w >> 1) * 16, kh = (w & 1) * 16;

    if (t < 32) lsum[t] = 0.f;

    // stage Q tile once: [32][512] bf16
    #pragma unroll
    for (int i = 0; i < 8; ++i) {
        int c = i * 256 + t;
        int row = c >> 6, cc = c & 63;
        async_copy16(Qg + (bS + q0 + row) * 512 + cc * 8, sQ + c * 8);
    }

    f32x4 oacc[16] = {};   // [c4][qt][dt]

    for (int kt = 0; kt < 9; ++kt) {
        int key0 = q0 - HALF_W + kt * 32;
        if (key0 + 32 <= 0 || key0 >= S_LEN) continue;   // block-uniform skip

        // ---- scores: S[32q][32k] = Q . K^T, D chunked by 128
        f32x4 sacc = {0.f, 0.f, 0.f, 0.f};
        for (int c4 = 0; c4 < 4; ++c4) {
            __syncthreads();
            #pragma unroll
            for (int i = 0; i < 2; ++i) {
                int c = i * 256 + t;
                int row = c >> 4, cc = c & 15;
                int rowg = key0 + row;
                rowg = (rowg < 0) ? 0 : ((rowg > S_LEN - 1) ? S_LEN - 1 : rowg);
                async_copy16(Kg + (bS + rowg) * 512 + c4 * 128 + cc * 8, sK + c * 8);
            }
            __syncthreads();
            #pragma unroll
            for (int kc = 0; kc < 4; ++kc) {
                bf16x8 aq = *(const bf16x8*)(sQ + (qh + l16) * 512 + c4 * 128 + kc * 32 + qd * 8);
                bf16x8 bk8 = *(const bf16x8*)(sK + (kh + l16) * 128 + kc * 32 + qd * 8);
                sacc = __builtin_amdgcn_mfma_f32_16x16x32_bf16(aq, bk8, sacc, 0, 0, 0);
            }
        }

        // ---- mask + exp + write P + row sums
        const float scale = 0.04419417382415922f;   // 1/sqrt(512)
        #pragma unroll
        for (int r = 0; r < 4; ++r) {
            int qi = q0 + qh + qd * 4 + r;
            int kj = key0 + kh + l16;
            bool valid = (kj >= 0) && (kj < S_LEN) && (kj >= qi - HALF_W) && (kj <= qi + HALF_W);
            float p = valid ? __expf(sacc[r] * scale) : 0.f;
            sP[(qh + qd * 4 + r) * 32 + kh + l16] = f2bf(p);
            float s = p;
            s += __shfl_xor(s, 1);
            s += __shfl_xor(s, 2);
            s += __shfl_xor(s, 4);
            s += __shfl_xor(s, 8);
            if (l16 == 0) atomicAdd(&lsum[qh + qd * 4 + r], s);
        }

        // ---- PV: O[32q][512d] += P . V, D chunked by 128; wave owns 32-d strip per chunk
        for (int c4 = 0; c4 < 4; ++c4) {
            __syncthreads();   // also publishes sP/lsum on c4==0
            #pragma unroll
            for (int i = 0; i < 2; ++i) {
                int c = i * 256 + t;
                int row = c >> 2, cc = c & 3;
                int kk = key0 + cc * 8;
                int koff = (kk >= 0 && kk + 8 <= S_LEN) ? kk : 0;   // clamped, masked via P=0
                async_copy16(Vt + (c4 * 128 + row) * M_TOT + bS + koff, sV + c * 8);
            }
            __syncthreads();
            #pragma unroll
            for (int qt = 0; qt < 2; ++qt) {
                bf16x8 ap = *(const bf16x8*)(sP + (qt * 16 + l16) * 32 + qd * 8);
                #pragma unroll
                for (int dt = 0; dt < 2; ++dt) {
                    bf16x8 bv8 = *(const bf16x8*)(sV + (w * 32 + dt * 16 + l16) * 32 + qd * 8);
                    oacc[c4 * 4 + qt * 2 + dt] =
                        __builtin_amdgcn_mfma_f32_16x16x32_bf16(ap, bv8, oacc[c4 * 4 + qt * 2 + dt], 0, 0, 0);
                }
            }
        }
    }

    __syncthreads();   // lsum final
    #pragma unroll
    for (int c4 = 0; c4 < 4; ++c4)
        #pragma unroll
        for (int qt = 0; qt < 2; ++qt)
            #pragma unroll
            for (int dt = 0; dt < 2; ++dt) {
                int dv = c4 * 128 + w * 32 + dt * 16 + l16;
                #pragma unroll
                for (int r = 0; r < 4; ++r) {
                    int q = qt * 16 + qd * 4 + r;
                    out[(bS + q0 + q) * 512 + dv] = oacc[c4 * 4 + qt * 2 + dt][r] / lsum[q];
                }
            }
}

// ---------------------------------------------------------------------------
extern "C" void kernel_launch(void* const* d_in, const int* in_sizes, int n_in,
                              void* d_out, int out_size, void* d_ws, size_t ws_size,
                              hipStream_t stream) {
    const float* x  = (const float*)d_in[0];
    const float* Wq = (const float*)d_in[1];
    const float* bq = (const float*)d_in[2];
    const float* Wk = (const float*)d_in[3];
    const float* bk = (const float*)d_in[4];
    const float* Wv = (const float*)d_in[5];
    const float* bv = (const float*)d_in[6];
    float* out = (float*)d_out;

    char* ws = (char*)d_ws;
    unsigned short* xb = (unsigned short*)(ws);                    // 16,777,216 B
    unsigned short* Wt = (unsigned short*)(ws + 16777216);         //  1,572,864 B
    unsigned short* Qb = (unsigned short*)(ws + 18350080);         // 16,777,216 B
    unsigned short* Kb = (unsigned short*)(ws + 35127296);         // 16,777,216 B
    unsigned short* Vt = (unsigned short*)(ws + 51904512);         // 16,777,216 B (transposed [512][16384])

    convert_x<<<8192, 256, 0, stream>>>(x, xb);
    convert_w<<<3072, 256, 0, stream>>>(Wq, Wk, Wv, Wt);
    qkv_gemm<<<dim3(128, 4, 3), 256, 0, stream>>>(xb, Wt, bq, bk, bv, Qb, Kb, Vt);
    attn<<<dim3(128, 4), 256, 0, stream>>>(Qb, Kb, Vt, out);
}

// Round 6
// 213.818 us; speedup vs baseline: 1.0798x; 1.0798x over previous
//
#include <hip/hip_runtime.h>
#include <hip/hip_bf16.h>

// Problem constants
#define S_LEN   4096
#define D_MOD   512
#define BATCH   4
#define HALF_W  128
#define M_TOT   (BATCH * S_LEN)   // 16384

typedef __attribute__((ext_vector_type(8))) short bf16x8;
typedef __attribute__((ext_vector_type(4))) float f32x4;

__device__ __forceinline__ unsigned short f2bf(float f) {
    // round-to-nearest-even bf16 (values are finite here)
    unsigned int u = __float_as_uint(f);
    unsigned int r = (u + 0x7fffu + ((u >> 16) & 1u)) >> 16;
    return (unsigned short)r;
}

__device__ __forceinline__ void async_copy16(const void* g, void* l) {
    __builtin_amdgcn_global_load_lds(
        (const __attribute__((address_space(1))) void*)g,
        (__attribute__((address_space(3))) void*)l, 16, 0, 0);
}

// ---------------------------------------------------------------------------
// Kernel 1: x fp32 -> bf16 (round-1 verbatim)
__global__ __launch_bounds__(256) void convert_x(const float* __restrict__ x,
                                                 unsigned short* __restrict__ xb) {
    int i = (blockIdx.x * 256 + threadIdx.x) * 4;
    float4 v = *(const float4*)(x + i);
    ushort4 o;
    o.x = f2bf(v.x); o.y = f2bf(v.y); o.z = f2bf(v.z); o.w = f2bf(v.w);
    *(ushort4*)(xb + i) = o;
}

// Kernel 2: W[k][n] fp32 -> Wt[n][k] bf16 (round-1 verbatim)
__global__ __launch_bounds__(256) void convert_w(const float* __restrict__ Wq,
                                                 const float* __restrict__ Wk,
                                                 const float* __restrict__ Wv,
                                                 unsigned short* __restrict__ Wt) {
    int idx = blockIdx.x * 256 + threadIdx.x;          // 3*512*512 total
    int w = idx >> 18;
    int rem = idx & 262143;
    int k = rem >> 9;
    int n = rem & 511;
    const float* W = (w == 0) ? Wq : ((w == 1) ? Wk : Wv);
    Wt[w * 262144 + n * 512 + k] = f2bf(W[k * 512 + n]);
}

// ---------------------------------------------------------------------------
// Kernel 3: fused QKV GEMM (round-1 verbatim except V-epilogue ushort4 stores).
// z=0 -> Q row-major, z=1 -> K row-major, z=2 -> V stored TRANSPOSED Vt[n][m].
__global__ __launch_bounds__(256) void qkv_gemm(
    const unsigned short* __restrict__ xb, const unsigned short* __restrict__ Wt,
    const float* __restrict__ bq, const float* __restrict__ bk, const float* __restrict__ bv,
    unsigned short* __restrict__ Qo, unsigned short* __restrict__ Ko,
    unsigned short* __restrict__ Vt) {
    __shared__ __align__(16) unsigned short sA[128 * 64];
    __shared__ __align__(16) unsigned short sB[128 * 64];

    const int t = threadIdx.x;
    const int m0 = blockIdx.x * 128;
    const int n0 = blockIdx.y * 128;
    const int wsel = blockIdx.z;
    const unsigned short* Wb = Wt + wsel * 262144;

    const int w = t >> 6, lane = t & 63;
    const int wm = (w & 1) * 64, wn = (w >> 1) * 64;
    const int qd = lane >> 4, l16 = lane & 15;

    f32x4 acc[4][4] = {};

    for (int k0 = 0; k0 < 512; k0 += 64) {
        __syncthreads();
        #pragma unroll
        for (int i = 0; i < 4; ++i) {
            int c = i * 256 + t;
            int row = c >> 3, cc = c & 7;
            async_copy16(xb + (m0 + row) * 512 + k0 + cc * 8, sA + c * 8);
            async_copy16(Wb + (n0 + row) * 512 + k0 + cc * 8, sB + c * 8);
        }
        __syncthreads();
        #pragma unroll
        for (int ks = 0; ks < 2; ++ks) {
            bf16x8 af[4], bfr[4];
            #pragma unroll
            for (int i = 0; i < 4; ++i)
                af[i] = *(const bf16x8*)(sA + (wm + i * 16 + l16) * 64 + ks * 32 + qd * 8);
            #pragma unroll
            for (int j = 0; j < 4; ++j)
                bfr[j] = *(const bf16x8*)(sB + (wn + j * 16 + l16) * 64 + ks * 32 + qd * 8);
            #pragma unroll
            for (int i = 0; i < 4; ++i)
                #pragma unroll
                for (int j = 0; j < 4; ++j)
                    acc[i][j] = __builtin_amdgcn_mfma_f32_16x16x32_bf16(af[i], bfr[j], acc[i][j], 0, 0, 0);
        }
    }

    const float* bias = (wsel == 0) ? bq : ((wsel == 1) ? bk : bv);
    if (wsel < 2) {
        unsigned short* Og = (wsel == 0) ? Qo : Ko;
        #pragma unroll
        for (int j = 0; j < 4; ++j) {
            int n = n0 + wn + j * 16 + l16;
            float bj = bias[n];
            #pragma unroll
            for (int i = 0; i < 4; ++i) {
                int mb = m0 + wm + i * 16 + qd * 4;
                #pragma unroll
                for (int r = 0; r < 4; ++r)
                    Og[(mb + r) * 512 + n] = f2bf(acc[i][j][r] + bj);
            }
        }
    } else {
        #pragma unroll
        for (int j = 0; j < 4; ++j) {
            int n = n0 + wn + j * 16 + l16;
            float bj = bias[n];
            #pragma unroll
            for (int i = 0; i < 4; ++i) {
                int mb = m0 + wm + i * 16 + qd * 4;
                ushort4 o;   // same addresses/values as r1's 4 scalar stores
                o.x = f2bf(acc[i][j][0] + bj);
                o.y = f2bf(acc[i][j][1] + bj);
                o.z = f2bf(acc[i][j][2] + bj);
                o.w = f2bf(acc[i][j][3] + bj);
                *(ushort4*)(Vt + (size_t)n * M_TOT + mb) = o;
            }
        }
    }
}

// ---------------------------------------------------------------------------
// Kernel 4: banded attention — round-1 structure verbatim, with three surgical
// fixes: (a) sQ/sK rows padded to 520 (stage rows are wave-uniform, so the
// global_load_lds dest stays wave-uniform-base + lane*16); (b) sK staged as
// the full 32x512 tile once per kt (2 barriers instead of 8 for scores);
// (c) sP stride 40. Everything else byte-identical to round 1.
__global__ __launch_bounds__(256) void attn(const unsigned short* __restrict__ Qg,
                                            const unsigned short* __restrict__ Kg,
                                            const unsigned short* __restrict__ Vt,
                                            float* __restrict__ out) {
    __shared__ __align__(16) unsigned short sQ[32 * 520];   // 33,280 B (padded)
    __shared__ __align__(16) unsigned short sK[32 * 520];   // 33,280 B (padded, full D)
    __shared__ __align__(16) unsigned short sV[128 * 32];   //  8,192 B (r1-exact)
    __shared__ __align__(16) unsigned short sP[32 * 40];    //  2,560 B (padded)
    __shared__ float lsum[32];

    const int t = threadIdx.x;
    const int q0 = blockIdx.x * 32;      // query offset within batch
    const int b = blockIdx.y;
    const int bS = b * S_LEN;
    const int w = t >> 6, lane = t & 63;
    const int qd = lane >> 4, l16 = lane & 15;
    const int qh = (w >> 1) * 16, kh = (w & 1) * 16;

    if (t < 32) lsum[t] = 0.f;

    // stage Q tile once: [32][512] bf16, rows padded to 520 (row = c>>6 is
    // wave-uniform -> dest = row*1040B + lane*16B, lane-linear)
    #pragma unroll
    for (int i = 0; i < 8; ++i) {
        int c = i * 256 + t;
        int row = c >> 6, cc = c & 63;
        async_copy16(Qg + (bS + q0 + row) * 512 + cc * 8, sQ + row * 520 + cc * 8);
    }

    f32x4 oacc[16] = {};   // [c4][qt][dt]

    for (int kt = 0; kt < 9; ++kt) {
        int key0 = q0 - HALF_W + kt * 32;
        if (key0 + 32 <= 0 || key0 >= S_LEN) continue;   // block-uniform skip

        // ---- stage full K tile [32][512] (same pattern as sQ)
        __syncthreads();
        #pragma unroll
        for (int i = 0; i < 8; ++i) {
            int c = i * 256 + t;
            int row = c >> 6, cc = c & 63;
            int rowg = key0 + row;
            rowg = (rowg < 0) ? 0 : ((rowg > S_LEN - 1) ? S_LEN - 1 : rowg);
            async_copy16(Kg + (bS + rowg) * 512 + cc * 8, sK + row * 520 + cc * 8);
        }
        __syncthreads();

        // ---- scores: S[32q][32k] = Q . K^T over full D (no barriers inside)
        f32x4 sacc = {0.f, 0.f, 0.f, 0.f};
        #pragma unroll
        for (int c4 = 0; c4 < 4; ++c4) {
            #pragma unroll
            for (int kc = 0; kc < 4; ++kc) {
                bf16x8 aq = *(const bf16x8*)(sQ + (qh + l16) * 520 + c4 * 128 + kc * 32 + qd * 8);
                bf16x8 bk8 = *(const bf16x8*)(sK + (kh + l16) * 520 + c4 * 128 + kc * 32 + qd * 8);
                sacc = __builtin_amdgcn_mfma_f32_16x16x32_bf16(aq, bk8, sacc, 0, 0, 0);
            }
        }

        // ---- mask + exp + write P + row sums (r1-verbatim, sP stride 40)
        const float scale = 0.04419417382415922f;   // 1/sqrt(512)
        #pragma unroll
        for (int r = 0; r < 4; ++r) {
            int qi = q0 + qh + qd * 4 + r;
            int kj = key0 + kh + l16;
            bool valid = (kj >= 0) && (kj < S_LEN) && (kj >= qi - HALF_W) && (kj <= qi + HALF_W);
            float p = valid ? __expf(sacc[r] * scale) : 0.f;
            sP[(qh + qd * 4 + r) * 40 + kh + l16] = f2bf(p);
            float s = p;
            s += __shfl_xor(s, 1);
            s += __shfl_xor(s, 2);
            s += __shfl_xor(s, 4);
            s += __shfl_xor(s, 8);
            if (l16 == 0) atomicAdd(&lsum[qh + qd * 4 + r], s);
        }

        // ---- PV: O[32q][512d] += P . V, D chunked by 128 (r1-verbatim)
        for (int c4 = 0; c4 < 4; ++c4) {
            __syncthreads();   // also publishes sP/lsum on c4==0
            #pragma unroll
            for (int i = 0; i < 2; ++i) {
                int c = i * 256 + t;
                int row = c >> 2, cc = c & 3;
                int kk = key0 + cc * 8;
                int koff = (kk >= 0 && kk + 8 <= S_LEN) ? kk : 0;   // clamped, masked via P=0
                async_copy16(Vt + (c4 * 128 + row) * M_TOT + bS + koff, sV + c * 8);
            }
            __syncthreads();
            #pragma unroll
            for (int qt = 0; qt < 2; ++qt) {
                bf16x8 ap = *(const bf16x8*)(sP + (qt * 16 + l16) * 40 + qd * 8);
                #pragma unroll
                for (int dt = 0; dt < 2; ++dt) {
                    bf16x8 bv8 = *(const bf16x8*)(sV + (w * 32 + dt * 16 + l16) * 32 + qd * 8);
                    oacc[c4 * 4 + qt * 2 + dt] =
                        __builtin_amdgcn_mfma_f32_16x16x32_bf16(ap, bv8, oacc[c4 * 4 + qt * 2 + dt], 0, 0, 0);
                }
            }
        }
    }

    __syncthreads();   // lsum final
    #pragma unroll
    for (int c4 = 0; c4 < 4; ++c4)
        #pragma unroll
        for (int qt = 0; qt < 2; ++qt)
            #pragma unroll
            for (int dt = 0; dt < 2; ++dt) {
                int dv = c4 * 128 + w * 32 + dt * 16 + l16;
                #pragma unroll
                for (int r = 0; r < 4; ++r) {
                    int q = qt * 16 + qd * 4 + r;
                    out[(size_t)(bS + q0 + q) * 512 + dv] = oacc[c4 * 4 + qt * 2 + dt][r] / lsum[q];
                }
            }
}

// ---------------------------------------------------------------------------
extern "C" void kernel_launch(void* const* d_in, const int* in_sizes, int n_in,
                              void* d_out, int out_size, void* d_ws, size_t ws_size,
                              hipStream_t stream) {
    const float* x  = (const float*)d_in[0];
    const float* Wq = (const float*)d_in[1];
    const float* bq = (const float*)d_in[2];
    const float* Wk = (const float*)d_in[3];
    const float* bk = (const float*)d_in[4];
    const float* Wv = (const float*)d_in[5];
    const float* bv = (const float*)d_in[6];
    float* out = (float*)d_out;

    char* ws = (char*)d_ws;
    unsigned short* xb = (unsigned short*)(ws);                    // 16 MB
    unsigned short* Wt = (unsigned short*)(ws + 16777216);         // 1.5 MB
    unsigned short* Qb = (unsigned short*)(ws + 18350080);         // 16 MB
    unsigned short* Kb = (unsigned short*)(ws + 35127296);         // 16 MB
    unsigned short* Vt = (unsigned short*)(ws + 51904512);         // 16 MB, [512][16384]

    convert_x<<<8192, 256, 0, stream>>>(x, xb);
    convert_w<<<3072, 256, 0, stream>>>(Wq, Wk, Wv, Wt);
    qkv_gemm<<<dim3(128, 4, 3), 256, 0, stream>>>(xb, Wt, bq, bk, bv, Qb, Kb, Vt);
    attn<<<dim3(128, 4), 256, 0, stream>>>(Qb, Kb, Vt, out);
}

// Round 7
// 208.408 us; speedup vs baseline: 1.1079x; 1.0260x over previous
//
#include <hip/hip_runtime.h>
#include <hip/hip_bf16.h>

// Problem constants
#define S_LEN   4096
#define D_MOD   512
#define BATCH   4
#define HALF_W  128
#define M_TOT   (BATCH * S_LEN)   // 16384

typedef __attribute__((ext_vector_type(8))) short bf16x8;
typedef __attribute__((ext_vector_type(4))) float f32x4;

__device__ __forceinline__ unsigned short f2bf(float f) {
    // round-to-nearest-even bf16 (values are finite here)
    unsigned int u = __float_as_uint(f);
    unsigned int r = (u + 0x7fffu + ((u >> 16) & 1u)) >> 16;
    return (unsigned short)r;
}

__device__ __forceinline__ void async_copy16(const void* g, void* l) {
    __builtin_amdgcn_global_load_lds(
        (const __attribute__((address_space(1))) void*)g,
        (__attribute__((address_space(3))) void*)l, 16, 0, 0);
}

// ---------------------------------------------------------------------------
// Kernel 1: x fp32 -> bf16 (round-1 verbatim)
__global__ __launch_bounds__(256) void convert_x(const float* __restrict__ x,
                                                 unsigned short* __restrict__ xb) {
    int i = (blockIdx.x * 256 + threadIdx.x) * 4;
    float4 v = *(const float4*)(x + i);
    ushort4 o;
    o.x = f2bf(v.x); o.y = f2bf(v.y); o.z = f2bf(v.z); o.w = f2bf(v.w);
    *(ushort4*)(xb + i) = o;
}

// Kernel 2: W[k][n] fp32 -> Wt[n][k] bf16, tiled LDS transpose (coalesced both sides)
__global__ __launch_bounds__(256) void convert_w(const float* __restrict__ Wq,
                                                 const float* __restrict__ Wk,
                                                 const float* __restrict__ Wv,
                                                 unsigned short* __restrict__ Wt) {
    __shared__ float sT[64][65];
    const int t = threadIdx.x;
    const int w = blockIdx.z;
    const float* W = (w == 0) ? Wq : ((w == 1) ? Wk : Wv);
    const int n0 = blockIdx.x * 64, k0 = blockIdx.y * 64;
    const int r = t >> 4, c4 = (t & 15) * 4;
    #pragma unroll
    for (int i = 0; i < 4; ++i) {
        float4 v = *(const float4*)(W + (size_t)(k0 + r + i * 16) * 512 + n0 + c4);
        sT[c4 + 0][r + i * 16] = v.x;
        sT[c4 + 1][r + i * 16] = v.y;
        sT[c4 + 2][r + i * 16] = v.z;
        sT[c4 + 3][r + i * 16] = v.w;
    }
    __syncthreads();
    #pragma unroll
    for (int i = 0; i < 4; ++i) {
        int rr = (t >> 4) + i * 16;   // n-local
        ushort4 o;
        o.x = f2bf(sT[rr][c4 + 0]);
        o.y = f2bf(sT[rr][c4 + 1]);
        o.z = f2bf(sT[rr][c4 + 2]);
        o.w = f2bf(sT[rr][c4 + 3]);
        *(ushort4*)(Wt + (size_t)w * 262144 + (size_t)(n0 + rr) * 512 + k0 + c4) = o;
    }
}

// ---------------------------------------------------------------------------
// Kernel 3: fused QKV GEMM, 128x128 tile, BK=64. LDS-staged vectorized epilogue.
// z=0 -> Q row-major, z=1 -> K row-major, z=2 -> V transposed Vt[n][m].
__global__ __launch_bounds__(256) void qkv_gemm(
    const unsigned short* __restrict__ xb, const unsigned short* __restrict__ Wt,
    const float* __restrict__ bq, const float* __restrict__ bk, const float* __restrict__ bv,
    unsigned short* __restrict__ Qo, unsigned short* __restrict__ Ko,
    unsigned short* __restrict__ Vt) {
    __shared__ __align__(16) char gsmem[34816];
    unsigned short* sA = (unsigned short*)gsmem;            // [128][64]
    unsigned short* sB = (unsigned short*)(gsmem + 16384);  // [128][64]
    unsigned short* sT = (unsigned short*)gsmem;            // [128][136] epilogue

    const int t = threadIdx.x;
    const int m0 = blockIdx.x * 128;
    const int n0 = blockIdx.y * 128;
    const int wsel = blockIdx.z;
    const unsigned short* Wb = Wt + (size_t)wsel * 262144;

    const int w = t >> 6, lane = t & 63;
    const int wm = (w & 1) * 64, wn = (w >> 1) * 64;
    const int qd = lane >> 4, l16 = lane & 15;

    f32x4 acc[4][4] = {};

    for (int k0 = 0; k0 < 512; k0 += 64) {
        __syncthreads();
        #pragma unroll
        for (int i = 0; i < 4; ++i) {
            int c = i * 256 + t;
            int row = c >> 3, cc = c & 7;
            async_copy16(xb + (size_t)(m0 + row) * 512 + k0 + cc * 8, sA + c * 8);
            async_copy16(Wb + (size_t)(n0 + row) * 512 + k0 + cc * 8, sB + c * 8);
        }
        __syncthreads();
        #pragma unroll
        for (int ks = 0; ks < 2; ++ks) {
            bf16x8 af[4], bfr[4];
            #pragma unroll
            for (int i = 0; i < 4; ++i)
                af[i] = *(const bf16x8*)(sA + (wm + i * 16 + l16) * 64 + ks * 32 + qd * 8);
            #pragma unroll
            for (int j = 0; j < 4; ++j)
                bfr[j] = *(const bf16x8*)(sB + (wn + j * 16 + l16) * 64 + ks * 32 + qd * 8);
            #pragma unroll
            for (int i = 0; i < 4; ++i)
                #pragma unroll
                for (int j = 0; j < 4; ++j)
                    acc[i][j] = __builtin_amdgcn_mfma_f32_16x16x32_bf16(af[i], bfr[j], acc[i][j], 0, 0, 0);
        }
    }

    const float* bias = (wsel == 0) ? bq : ((wsel == 1) ? bk : bv);
    __syncthreads();   // done reading sA/sB; sT aliases them

    if (wsel < 2) {
        // stage row-major sT[m][n] (stride 136)
        #pragma unroll
        for (int j = 0; j < 4; ++j) {
            int n = wn + j * 16 + l16;
            float bj = bias[n0 + n];
            #pragma unroll
            for (int i = 0; i < 4; ++i) {
                int mb = wm + i * 16 + qd * 4;
                #pragma unroll
                for (int r = 0; r < 4; ++r)
                    sT[(mb + r) * 136 + n] = f2bf(acc[i][j][r] + bj);
            }
        }
        __syncthreads();
        unsigned short* Og = (wsel == 0) ? Qo : Ko;
        #pragma unroll
        for (int i2 = 0; i2 < 4; ++i2)
            #pragma unroll
            for (int i3 = 0; i3 < 2; ++i3) {
                int m = i2 * 32 + (t >> 3);
                int ch = (t & 7) + i3 * 8;
                bf16x8 v = *(const bf16x8*)(sT + m * 136 + ch * 8);
                *(bf16x8*)(Og + (size_t)(m0 + m) * 512 + n0 + ch * 8) = v;
            }
    } else {
        // stage transposed sT[n][m] (stride 136)
        #pragma unroll
        for (int j = 0; j < 4; ++j) {
            int n = wn + j * 16 + l16;
            float bj = bias[n0 + n];
            #pragma unroll
            for (int i = 0; i < 4; ++i) {
                int mb = wm + i * 16 + qd * 4;
                #pragma unroll
                for (int r = 0; r < 4; ++r)
                    sT[n * 136 + mb + r] = f2bf(acc[i][j][r] + bj);
            }
        }
        __syncthreads();
        #pragma unroll
        for (int i2 = 0; i2 < 4; ++i2)
            #pragma unroll
            for (int i3 = 0; i3 < 2; ++i3) {
                int n = i2 * 32 + (t >> 3);
                int ch = (t & 7) + i3 * 8;
                bf16x8 v = *(const bf16x8*)(sT + n * 136 + ch * 8);
                *(bf16x8*)(Vt + (size_t)(n0 + n) * M_TOT + m0 + ch * 8) = v;
            }
    }
}

// ---------------------------------------------------------------------------
// Kernel 4: banded attention — round-6 PASSING version, byte-identical.
__global__ __launch_bounds__(256) void attn(const unsigned short* __restrict__ Qg,
                                            const unsigned short* __restrict__ Kg,
                                            const unsigned short* __restrict__ Vt,
                                            float* __restrict__ out) {
    __shared__ __align__(16) unsigned short sQ[32 * 520];   // 33,280 B (padded)
    __shared__ __align__(16) unsigned short sK[32 * 520];   // 33,280 B (padded, full D)
    __shared__ __align__(16) unsigned short sV[128 * 32];   //  8,192 B
    __shared__ __align__(16) unsigned short sP[32 * 40];    //  2,560 B (padded)
    __shared__ float lsum[32];

    const int t = threadIdx.x;
    const int q0 = blockIdx.x * 32;      // query offset within batch
    const int b = blockIdx.y;
    const int bS = b * S_LEN;
    const int w = t >> 6, lane = t & 63;
    const int qd = lane >> 4, l16 = lane & 15;
    const int qh = (w >> 1) * 16, kh = (w & 1) * 16;

    if (t < 32) lsum[t] = 0.f;

    // stage Q tile once: [32][512] bf16, rows padded to 520
    #pragma unroll
    for (int i = 0; i < 8; ++i) {
        int c = i * 256 + t;
        int row = c >> 6, cc = c & 63;
        async_copy16(Qg + (bS + q0 + row) * 512 + cc * 8, sQ + row * 520 + cc * 8);
    }

    f32x4 oacc[16] = {};   // [c4][qt][dt]

    for (int kt = 0; kt < 9; ++kt) {
        int key0 = q0 - HALF_W + kt * 32;
        if (key0 + 32 <= 0 || key0 >= S_LEN) continue;   // block-uniform skip

        // ---- stage full K tile [32][512]
        __syncthreads();
        #pragma unroll
        for (int i = 0; i < 8; ++i) {
            int c = i * 256 + t;
            int row = c >> 6, cc = c & 63;
            int rowg = key0 + row;
            rowg = (rowg < 0) ? 0 : ((rowg > S_LEN - 1) ? S_LEN - 1 : rowg);
            async_copy16(Kg + (bS + rowg) * 512 + cc * 8, sK + row * 520 + cc * 8);
        }
        __syncthreads();

        // ---- scores: S[32q][32k] = Q . K^T over full D
        f32x4 sacc = {0.f, 0.f, 0.f, 0.f};
        #pragma unroll
        for (int c4 = 0; c4 < 4; ++c4) {
            #pragma unroll
            for (int kc = 0; kc < 4; ++kc) {
                bf16x8 aq = *(const bf16x8*)(sQ + (qh + l16) * 520 + c4 * 128 + kc * 32 + qd * 8);
                bf16x8 bk8 = *(const bf16x8*)(sK + (kh + l16) * 520 + c4 * 128 + kc * 32 + qd * 8);
                sacc = __builtin_amdgcn_mfma_f32_16x16x32_bf16(aq, bk8, sacc, 0, 0, 0);
            }
        }

        // ---- mask + exp + write P + row sums
        const float scale = 0.04419417382415922f;   // 1/sqrt(512)
        #pragma unroll
        for (int r = 0; r < 4; ++r) {
            int qi = q0 + qh + qd * 4 + r;
            int kj = key0 + kh + l16;
            bool valid = (kj >= 0) && (kj < S_LEN) && (kj >= qi - HALF_W) && (kj <= qi + HALF_W);
            float p = valid ? __expf(sacc[r] * scale) : 0.f;
            sP[(qh + qd * 4 + r) * 40 + kh + l16] = f2bf(p);
            float s = p;
            s += __shfl_xor(s, 1);
            s += __shfl_xor(s, 2);
            s += __shfl_xor(s, 4);
            s += __shfl_xor(s, 8);
            if (l16 == 0) atomicAdd(&lsum[qh + qd * 4 + r], s);
        }

        // ---- PV: O[32q][512d] += P . V, D chunked by 128
        for (int c4 = 0; c4 < 4; ++c4) {
            __syncthreads();   // also publishes sP/lsum on c4==0
            #pragma unroll
            for (int i = 0; i < 2; ++i) {
                int c = i * 256 + t;
                int row = c >> 2, cc = c & 3;
                int kk = key0 + cc * 8;
                int koff = (kk >= 0 && kk + 8 <= S_LEN) ? kk : 0;   // clamped, masked via P=0
                async_copy16(Vt + (c4 * 128 + row) * M_TOT + bS + koff, sV + c * 8);
            }
            __syncthreads();
            #pragma unroll
            for (int qt = 0; qt < 2; ++qt) {
                bf16x8 ap = *(const bf16x8*)(sP + (qt * 16 + l16) * 40 + qd * 8);
                #pragma unroll
                for (int dt = 0; dt < 2; ++dt) {
                    bf16x8 bv8 = *(const bf16x8*)(sV + (w * 32 + dt * 16 + l16) * 32 + qd * 8);
                    oacc[c4 * 4 + qt * 2 + dt] =
                        __builtin_amdgcn_mfma_f32_16x16x32_bf16(ap, bv8, oacc[c4 * 4 + qt * 2 + dt], 0, 0, 0);
                }
            }
        }
    }

    __syncthreads();   // lsum final
    #pragma unroll
    for (int c4 = 0; c4 < 4; ++c4)
        #pragma unroll
        for (int qt = 0; qt < 2; ++qt)
            #pragma unroll
            for (int dt = 0; dt < 2; ++dt) {
                int dv = c4 * 128 + w * 32 + dt * 16 + l16;
                #pragma unroll
                for (int r = 0; r < 4; ++r) {
                    int q = qt * 16 + qd * 4 + r;
                    out[(size_t)(bS + q0 + q) * 512 + dv] = oacc[c4 * 4 + qt * 2 + dt][r] / lsum[q];
                }
            }
}

// ---------------------------------------------------------------------------
extern "C" void kernel_launch(void* const* d_in, const int* in_sizes, int n_in,
                              void* d_out, int out_size, void* d_ws, size_t ws_size,
                              hipStream_t stream) {
    const float* x  = (const float*)d_in[0];
    const float* Wq = (const float*)d_in[1];
    const float* bq = (const float*)d_in[2];
    const float* Wk = (const float*)d_in[3];
    const float* bk = (const float*)d_in[4];
    const float* Wv = (const float*)d_in[5];
    const float* bv = (const float*)d_in[6];
    float* out = (float*)d_out;

    char* ws = (char*)d_ws;
    unsigned short* xb = (unsigned short*)(ws);                    // 16 MB
    unsigned short* Wt = (unsigned short*)(ws + 16777216);         // 1.5 MB
    unsigned short* Qb = (unsigned short*)(ws + 18350080);         // 16 MB
    unsigned short* Kb = (unsigned short*)(ws + 35127296);         // 16 MB
    unsigned short* Vt = (unsigned short*)(ws + 51904512);         // 16 MB, [512][16384]

    convert_x<<<8192, 256, 0, stream>>>(x, xb);
    convert_w<<<dim3(8, 8, 3), 256, 0, stream>>>(Wq, Wk, Wv, Wt);
    qkv_gemm<<<dim3(128, 4, 3), 256, 0, stream>>>(xb, Wt, bq, bk, bv, Qb, Kb, Vt);
    attn<<<dim3(128, 4), 256, 0, stream>>>(Qb, Kb, Vt, out);
}

// Round 8
// 207.458 us; speedup vs baseline: 1.1129x; 1.0046x over previous
//
#include <hip/hip_runtime.h>
#include <hip/hip_bf16.h>

// Problem constants
#define S_LEN   4096
#define D_MOD   512
#define BATCH   4
#define HALF_W  128
#define M_TOT   (BATCH * S_LEN)   // 16384

typedef __attribute__((ext_vector_type(8))) short bf16x8;
typedef __attribute__((ext_vector_type(4))) float f32x4;

__device__ __forceinline__ unsigned short f2bf(float f) {
    // round-to-nearest-even bf16 (values are finite here)
    unsigned int u = __float_as_uint(f);
    unsigned int r = (u + 0x7fffu + ((u >> 16) & 1u)) >> 16;
    return (unsigned short)r;
}

__device__ __forceinline__ void async_copy16(const void* g, void* l) {
    __builtin_amdgcn_global_load_lds(
        (const __attribute__((address_space(1))) void*)g,
        (__attribute__((address_space(3))) void*)l, 16, 0, 0);
}

// ---------------------------------------------------------------------------
// Kernel 1: x fp32 -> bf16 (round-1 verbatim)
__global__ __launch_bounds__(256) void convert_x(const float* __restrict__ x,
                                                 unsigned short* __restrict__ xb) {
    int i = (blockIdx.x * 256 + threadIdx.x) * 4;
    float4 v = *(const float4*)(x + i);
    ushort4 o;
    o.x = f2bf(v.x); o.y = f2bf(v.y); o.z = f2bf(v.z); o.w = f2bf(v.w);
    *(ushort4*)(xb + i) = o;
}

// Kernel 2: W[k][n] fp32 -> Wt[n][k] bf16, tiled LDS transpose (r7-passing)
__global__ __launch_bounds__(256) void convert_w(const float* __restrict__ Wq,
                                                 const float* __restrict__ Wk,
                                                 const float* __restrict__ Wv,
                                                 unsigned short* __restrict__ Wt) {
    __shared__ float sT[64][65];
    const int t = threadIdx.x;
    const int w = blockIdx.z;
    const float* W = (w == 0) ? Wq : ((w == 1) ? Wk : Wv);
    const int n0 = blockIdx.x * 64, k0 = blockIdx.y * 64;
    const int r = t >> 4, c4 = (t & 15) * 4;
    #pragma unroll
    for (int i = 0; i < 4; ++i) {
        float4 v = *(const float4*)(W + (size_t)(k0 + r + i * 16) * 512 + n0 + c4);
        sT[c4 + 0][r + i * 16] = v.x;
        sT[c4 + 1][r + i * 16] = v.y;
        sT[c4 + 2][r + i * 16] = v.z;
        sT[c4 + 3][r + i * 16] = v.w;
    }
    __syncthreads();
    #pragma unroll
    for (int i = 0; i < 4; ++i) {
        int rr = (t >> 4) + i * 16;   // n-local
        ushort4 o;
        o.x = f2bf(sT[rr][c4 + 0]);
        o.y = f2bf(sT[rr][c4 + 1]);
        o.z = f2bf(sT[rr][c4 + 2]);
        o.w = f2bf(sT[rr][c4 + 3]);
        *(ushort4*)(Wt + (size_t)w * 262144 + (size_t)(n0 + rr) * 512 + k0 + c4) = o;
    }
}

// ---------------------------------------------------------------------------
// Kernel 3: fused QKV GEMM (r7-passing, byte-identical).
__global__ __launch_bounds__(256) void qkv_gemm(
    const unsigned short* __restrict__ xb, const unsigned short* __restrict__ Wt,
    const float* __restrict__ bq, const float* __restrict__ bk, const float* __restrict__ bv,
    unsigned short* __restrict__ Qo, unsigned short* __restrict__ Ko,
    unsigned short* __restrict__ Vt) {
    __shared__ __align__(16) char gsmem[34816];
    unsigned short* sA = (unsigned short*)gsmem;            // [128][64]
    unsigned short* sB = (unsigned short*)(gsmem + 16384);  // [128][64]
    unsigned short* sT = (unsigned short*)gsmem;            // [128][136] epilogue

    const int t = threadIdx.x;
    const int m0 = blockIdx.x * 128;
    const int n0 = blockIdx.y * 128;
    const int wsel = blockIdx.z;
    const unsigned short* Wb = Wt + (size_t)wsel * 262144;

    const int w = t >> 6, lane = t & 63;
    const int wm = (w & 1) * 64, wn = (w >> 1) * 64;
    const int qd = lane >> 4, l16 = lane & 15;

    f32x4 acc[4][4] = {};

    for (int k0 = 0; k0 < 512; k0 += 64) {
        __syncthreads();
        #pragma unroll
        for (int i = 0; i < 4; ++i) {
            int c = i * 256 + t;
            int row = c >> 3, cc = c & 7;
            async_copy16(xb + (size_t)(m0 + row) * 512 + k0 + cc * 8, sA + c * 8);
            async_copy16(Wb + (size_t)(n0 + row) * 512 + k0 + cc * 8, sB + c * 8);
        }
        __syncthreads();
        #pragma unroll
        for (int ks = 0; ks < 2; ++ks) {
            bf16x8 af[4], bfr[4];
            #pragma unroll
            for (int i = 0; i < 4; ++i)
                af[i] = *(const bf16x8*)(sA + (wm + i * 16 + l16) * 64 + ks * 32 + qd * 8);
            #pragma unroll
            for (int j = 0; j < 4; ++j)
                bfr[j] = *(const bf16x8*)(sB + (wn + j * 16 + l16) * 64 + ks * 32 + qd * 8);
            #pragma unroll
            for (int i = 0; i < 4; ++i)
                #pragma unroll
                for (int j = 0; j < 4; ++j)
                    acc[i][j] = __builtin_amdgcn_mfma_f32_16x16x32_bf16(af[i], bfr[j], acc[i][j], 0, 0, 0);
        }
    }

    const float* bias = (wsel == 0) ? bq : ((wsel == 1) ? bk : bv);
    __syncthreads();   // done reading sA/sB; sT aliases them

    if (wsel < 2) {
        #pragma unroll
        for (int j = 0; j < 4; ++j) {
            int n = wn + j * 16 + l16;
            float bj = bias[n0 + n];
            #pragma unroll
            for (int i = 0; i < 4; ++i) {
                int mb = wm + i * 16 + qd * 4;
                #pragma unroll
                for (int r = 0; r < 4; ++r)
                    sT[(mb + r) * 136 + n] = f2bf(acc[i][j][r] + bj);
            }
        }
        __syncthreads();
        unsigned short* Og = (wsel == 0) ? Qo : Ko;
        #pragma unroll
        for (int i2 = 0; i2 < 4; ++i2)
            #pragma unroll
            for (int i3 = 0; i3 < 2; ++i3) {
                int m = i2 * 32 + (t >> 3);
                int ch = (t & 7) + i3 * 8;
                bf16x8 v = *(const bf16x8*)(sT + m * 136 + ch * 8);
                *(bf16x8*)(Og + (size_t)(m0 + m) * 512 + n0 + ch * 8) = v;
            }
    } else {
        #pragma unroll
        for (int j = 0; j < 4; ++j) {
            int n = wn + j * 16 + l16;
            float bj = bias[n0 + n];
            #pragma unroll
            for (int i = 0; i < 4; ++i) {
                int mb = wm + i * 16 + qd * 4;
                #pragma unroll
                for (int r = 0; r < 4; ++r)
                    sT[n * 136 + mb + r] = f2bf(acc[i][j][r] + bj);
            }
        }
        __syncthreads();
        #pragma unroll
        for (int i2 = 0; i2 < 4; ++i2)
            #pragma unroll
            for (int i3 = 0; i3 < 2; ++i3) {
                int n = i2 * 32 + (t >> 3);
                int ch = (t & 7) + i3 * 8;
                bf16x8 v = *(const bf16x8*)(sT + n * 136 + ch * 8);
                *(bf16x8*)(Vt + (size_t)(n0 + n) * M_TOT + m0 + ch * 8) = v;
            }
    }
}

// ---------------------------------------------------------------------------
// Kernel 4: banded attention — r6-passing compute, restructured staging:
// one shared 33 KB LDS buffer holds K[32][520] during scores, then V[512][32]
// during PV. Full V tile staged in ONE round -> 4 barriers/kt instead of 10.
// All indexing byte-identical to the r6-passing version.
__global__ __launch_bounds__(256) void attn(const unsigned short* __restrict__ Qg,
                                            const unsigned short* __restrict__ Kg,
                                            const unsigned short* __restrict__ Vt,
                                            float* __restrict__ out) {
    __shared__ __align__(16) unsigned short sQ[32 * 520];    // 33,280 B (padded)
    __shared__ __align__(16) unsigned short sKV[32 * 520];   // 33,280 B: K[32][520] | V[512][32]
    __shared__ __align__(16) unsigned short sP[32 * 40];     //  2,560 B (padded)
    __shared__ float lsum[32];

    const int t = threadIdx.x;
    const int q0 = blockIdx.x * 32;      // query offset within batch
    const int b = blockIdx.y;
    const int bS = b * S_LEN;
    const int w = t >> 6, lane = t & 63;
    const int qd = lane >> 4, l16 = lane & 15;
    const int qh = (w >> 1) * 16, kh = (w & 1) * 16;

    if (t < 32) lsum[t] = 0.f;

    // stage Q tile once: [32][512] bf16, rows padded to 520
    #pragma unroll
    for (int i = 0; i < 8; ++i) {
        int c = i * 256 + t;
        int row = c >> 6, cc = c & 63;
        async_copy16(Qg + (bS + q0 + row) * 512 + cc * 8, sQ + row * 520 + cc * 8);
    }

    f32x4 oacc[16] = {};   // [c4][qt][dt]

    for (int kt = 0; kt < 9; ++kt) {
        int key0 = q0 - HALF_W + kt * 32;
        if (key0 + 32 <= 0 || key0 >= S_LEN) continue;   // block-uniform skip

        // ---- (a) previous V reads done; stage full K tile [32][520-padded]
        __syncthreads();
        #pragma unroll
        for (int i = 0; i < 8; ++i) {
            int c = i * 256 + t;
            int row = c >> 6, cc = c & 63;
            int rowg = key0 + row;
            rowg = (rowg < 0) ? 0 : ((rowg > S_LEN - 1) ? S_LEN - 1 : rowg);
            async_copy16(Kg + (bS + rowg) * 512 + cc * 8, sKV + row * 520 + cc * 8);
        }
        __syncthreads();   // (b) K ready

        // ---- scores: S[32q][32k] = Q . K^T over full D
        f32x4 sacc = {0.f, 0.f, 0.f, 0.f};
        #pragma unroll
        for (int c4 = 0; c4 < 4; ++c4) {
            #pragma unroll
            for (int kc = 0; kc < 4; ++kc) {
                bf16x8 aq = *(const bf16x8*)(sQ + (qh + l16) * 520 + c4 * 128 + kc * 32 + qd * 8);
                bf16x8 bk8 = *(const bf16x8*)(sKV + (kh + l16) * 520 + c4 * 128 + kc * 32 + qd * 8);
                sacc = __builtin_amdgcn_mfma_f32_16x16x32_bf16(aq, bk8, sacc, 0, 0, 0);
            }
        }

        // ---- mask + exp + write P + row sums
        const float scale = 0.04419417382415922f;   // 1/sqrt(512)
        #pragma unroll
        for (int r = 0; r < 4; ++r) {
            int qi = q0 + qh + qd * 4 + r;
            int kj = key0 + kh + l16;
            bool valid = (kj >= 0) && (kj < S_LEN) && (kj >= qi - HALF_W) && (kj <= qi + HALF_W);
            float p = valid ? __expf(sacc[r] * scale) : 0.f;
            sP[(qh + qd * 4 + r) * 40 + kh + l16] = f2bf(p);
            float s = p;
            s += __shfl_xor(s, 1);
            s += __shfl_xor(s, 2);
            s += __shfl_xor(s, 4);
            s += __shfl_xor(s, 8);
            if (l16 == 0) atomicAdd(&lsum[qh + qd * 4 + r], s);
        }

        // ---- (c) K reads done, sP published; stage FULL V tile [512][32]
        __syncthreads();
        #pragma unroll
        for (int i = 0; i < 8; ++i) {
            int c = i * 256 + t;
            int row = c >> 2, cc = c & 3;
            int kk = key0 + cc * 8;
            int koff = (kk >= 0 && kk + 8 <= S_LEN) ? kk : 0;   // clamped, masked via P=0
            async_copy16(Vt + (size_t)row * M_TOT + bS + koff, sKV + c * 8);
        }
        __syncthreads();   // (d) V ready

        // ---- PV: O[32q][512d] += P . V (no barriers inside)
        #pragma unroll
        for (int c4 = 0; c4 < 4; ++c4) {
            #pragma unroll
            for (int qt = 0; qt < 2; ++qt) {
                bf16x8 ap = *(const bf16x8*)(sP + (qt * 16 + l16) * 40 + qd * 8);
                #pragma unroll
                for (int dt = 0; dt < 2; ++dt) {
                    bf16x8 bv8 = *(const bf16x8*)(sKV + (c4 * 128 + w * 32 + dt * 16 + l16) * 32 + qd * 8);
                    oacc[c4 * 4 + qt * 2 + dt] =
                        __builtin_amdgcn_mfma_f32_16x16x32_bf16(ap, bv8, oacc[c4 * 4 + qt * 2 + dt], 0, 0, 0);
                }
            }
        }
    }

    __syncthreads();   // lsum final
    #pragma unroll
    for (int c4 = 0; c4 < 4; ++c4)
        #pragma unroll
        for (int qt = 0; qt < 2; ++qt)
            #pragma unroll
            for (int dt = 0; dt < 2; ++dt) {
                int dv = c4 * 128 + w * 32 + dt * 16 + l16;
                #pragma unroll
                for (int r = 0; r < 4; ++r) {
                    int q = qt * 16 + qd * 4 + r;
                    out[(size_t)(bS + q0 + q) * 512 + dv] = oacc[c4 * 4 + qt * 2 + dt][r] / lsum[q];
                }
            }
}

// ---------------------------------------------------------------------------
extern "C" void kernel_launch(void* const* d_in, const int* in_sizes, int n_in,
                              void* d_out, int out_size, void* d_ws, size_t ws_size,
                              hipStream_t stream) {
    const float* x  = (const float*)d_in[0];
    const float* Wq = (const float*)d_in[1];
    const float* bq = (const float*)d_in[2];
    const float* Wk = (const float*)d_in[3];
    const float* bk = (const float*)d_in[4];
    const float* Wv = (const float*)d_in[5];
    const float* bv = (const float*)d_in[6];
    float* out = (float*)d_out;

    char* ws = (char*)d_ws;
    unsigned short* xb = (unsigned short*)(ws);                    // 16 MB
    unsigned short* Wt = (unsigned short*)(ws + 16777216);         // 1.5 MB
    unsigned short* Qb = (unsigned short*)(ws + 18350080);         // 16 MB
    unsigned short* Kb = (unsigned short*)(ws + 35127296);         // 16 MB
    unsigned short* Vt = (unsigned short*)(ws + 51904512);         // 16 MB, [512][16384]

    convert_x<<<8192, 256, 0, stream>>>(x, xb);
    convert_w<<<dim3(8, 8, 3), 256, 0, stream>>>(Wq, Wk, Wv, Wt);
    qkv_gemm<<<dim3(128, 4, 3), 256, 0, stream>>>(xb, Wt, bq, bk, bv, Qb, Kb, Vt);
    attn<<<dim3(128, 4), 256, 0, stream>>>(Qb, Kb, Vt, out);
}

// Round 9
// 175.583 us; speedup vs baseline: 1.3150x; 1.1815x over previous
//
#include <hip/hip_runtime.h>
#include <hip/hip_bf16.h>

// Problem constants
#define S_LEN   4096
#define D_MOD   512
#define BATCH   4
#define HALF_W  128
#define M_TOT   (BATCH * S_LEN)   // 16384

typedef __attribute__((ext_vector_type(8))) short bf16x8;
typedef __attribute__((ext_vector_type(4))) float f32x4;

__device__ __forceinline__ unsigned short f2bf(float f) {
    // round-to-nearest-even bf16 (values are finite here)
    unsigned int u = __float_as_uint(f);
    unsigned int r = (u + 0x7fffu + ((u >> 16) & 1u)) >> 16;
    return (unsigned short)r;
}

__device__ __forceinline__ void async_copy16(const void* g, void* l) {
    __builtin_amdgcn_global_load_lds(
        (const __attribute__((address_space(1))) void*)g,
        (__attribute__((address_space(3))) void*)l, 16, 0, 0);
}

// ---------------------------------------------------------------------------
// Kernel 1: x fp32 -> bf16 (round-1 verbatim)
__global__ __launch_bounds__(256) void convert_x(const float* __restrict__ x,
                                                 unsigned short* __restrict__ xb) {
    int i = (blockIdx.x * 256 + threadIdx.x) * 4;
    float4 v = *(const float4*)(x + i);
    ushort4 o;
    o.x = f2bf(v.x); o.y = f2bf(v.y); o.z = f2bf(v.z); o.w = f2bf(v.w);
    *(ushort4*)(xb + i) = o;
}

// Kernel 2: W[k][n] fp32 -> Wt[n][k] bf16, tiled LDS transpose (r7-passing)
__global__ __launch_bounds__(256) void convert_w(const float* __restrict__ Wq,
                                                 const float* __restrict__ Wk,
                                                 const float* __restrict__ Wv,
                                                 unsigned short* __restrict__ Wt) {
    __shared__ float sT[64][65];
    const int t = threadIdx.x;
    const int w = blockIdx.z;
    const float* W = (w == 0) ? Wq : ((w == 1) ? Wk : Wv);
    const int n0 = blockIdx.x * 64, k0 = blockIdx.y * 64;
    const int r = t >> 4, c4 = (t & 15) * 4;
    #pragma unroll
    for (int i = 0; i < 4; ++i) {
        float4 v = *(const float4*)(W + (size_t)(k0 + r + i * 16) * 512 + n0 + c4);
        sT[c4 + 0][r + i * 16] = v.x;
        sT[c4 + 1][r + i * 16] = v.y;
        sT[c4 + 2][r + i * 16] = v.z;
        sT[c4 + 3][r + i * 16] = v.w;
    }
    __syncthreads();
    #pragma unroll
    for (int i = 0; i < 4; ++i) {
        int rr = (t >> 4) + i * 16;   // n-local
        ushort4 o;
        o.x = f2bf(sT[rr][c4 + 0]);
        o.y = f2bf(sT[rr][c4 + 1]);
        o.z = f2bf(sT[rr][c4 + 2]);
        o.w = f2bf(sT[rr][c4 + 3]);
        *(ushort4*)(Wt + (size_t)w * 262144 + (size_t)(n0 + rr) * 512 + k0 + c4) = o;
    }
}

// ---------------------------------------------------------------------------
// Kernel 3: fused QKV GEMM (r7-passing compute; 1-D grid with XCD swizzle:
// each XCD owns 16 consecutive m-tiles x all 12 (n,z) combos -> A-tile
// is L2-resident within its XCD instead of re-fetched by up to 8 XCDs).
__global__ __launch_bounds__(256) void qkv_gemm(
    const unsigned short* __restrict__ xb, const unsigned short* __restrict__ Wt,
    const float* __restrict__ bq, const float* __restrict__ bk, const float* __restrict__ bv,
    unsigned short* __restrict__ Qo, unsigned short* __restrict__ Ko,
    unsigned short* __restrict__ Vt) {
    __shared__ __align__(16) char gsmem[34816];
    unsigned short* sA = (unsigned short*)gsmem;            // [128][64]
    unsigned short* sB = (unsigned short*)(gsmem + 16384);  // [128][64]
    unsigned short* sT = (unsigned short*)gsmem;            // [128][136] epilogue

    const int t = threadIdx.x;
    // XCD swizzle: physical p -> xcd = p&7; each XCD gets 192 contiguous
    // logical blocks = 16 m-tiles * 12 (z,n) combos.
    const int p = blockIdx.x;
    const int l = (p & 7) * 192 + (p >> 3);
    const int mi = l / 12;
    const int rzn = l - mi * 12;
    const int wsel = rzn >> 2;
    const int ni = rzn & 3;
    const int m0 = mi * 128;
    const int n0 = ni * 128;
    const unsigned short* Wb = Wt + (size_t)wsel * 262144;

    const int w = t >> 6, lane = t & 63;
    const int wm = (w & 1) * 64, wn = (w >> 1) * 64;
    const int qd = lane >> 4, l16 = lane & 15;

    f32x4 acc[4][4] = {};

    for (int k0 = 0; k0 < 512; k0 += 64) {
        __syncthreads();
        #pragma unroll
        for (int i = 0; i < 4; ++i) {
            int c = i * 256 + t;
            int row = c >> 3, cc = c & 7;
            async_copy16(xb + (size_t)(m0 + row) * 512 + k0 + cc * 8, sA + c * 8);
            async_copy16(Wb + (size_t)(n0 + row) * 512 + k0 + cc * 8, sB + c * 8);
        }
        __syncthreads();
        #pragma unroll
        for (int ks = 0; ks < 2; ++ks) {
            bf16x8 af[4], bfr[4];
            #pragma unroll
            for (int i = 0; i < 4; ++i)
                af[i] = *(const bf16x8*)(sA + (wm + i * 16 + l16) * 64 + ks * 32 + qd * 8);
            #pragma unroll
            for (int j = 0; j < 4; ++j)
                bfr[j] = *(const bf16x8*)(sB + (wn + j * 16 + l16) * 64 + ks * 32 + qd * 8);
            #pragma unroll
            for (int i = 0; i < 4; ++i)
                #pragma unroll
                for (int j = 0; j < 4; ++j)
                    acc[i][j] = __builtin_amdgcn_mfma_f32_16x16x32_bf16(af[i], bfr[j], acc[i][j], 0, 0, 0);
        }
    }

    const float* bias = (wsel == 0) ? bq : ((wsel == 1) ? bk : bv);
    __syncthreads();   // done reading sA/sB; sT aliases them

    if (wsel < 2) {
        #pragma unroll
        for (int j = 0; j < 4; ++j) {
            int n = wn + j * 16 + l16;
            float bj = bias[n0 + n];
            #pragma unroll
            for (int i = 0; i < 4; ++i) {
                int mb = wm + i * 16 + qd * 4;
                #pragma unroll
                for (int r = 0; r < 4; ++r)
                    sT[(mb + r) * 136 + n] = f2bf(acc[i][j][r] + bj);
            }
        }
        __syncthreads();
        unsigned short* Og = (wsel == 0) ? Qo : Ko;
        #pragma unroll
        for (int i2 = 0; i2 < 4; ++i2)
            #pragma unroll
            for (int i3 = 0; i3 < 2; ++i3) {
                int m = i2 * 32 + (t >> 3);
                int ch = (t & 7) + i3 * 8;
                bf16x8 v = *(const bf16x8*)(sT + m * 136 + ch * 8);
                *(bf16x8*)(Og + (size_t)(m0 + m) * 512 + n0 + ch * 8) = v;
            }
    } else {
        #pragma unroll
        for (int j = 0; j < 4; ++j) {
            int n = wn + j * 16 + l16;
            float bj = bias[n0 + n];
            #pragma unroll
            for (int i = 0; i < 4; ++i) {
                int mb = wm + i * 16 + qd * 4;
                #pragma unroll
                for (int r = 0; r < 4; ++r)
                    sT[n * 136 + mb + r] = f2bf(acc[i][j][r] + bj);
            }
        }
        __syncthreads();
        #pragma unroll
        for (int i2 = 0; i2 < 4; ++i2)
            #pragma unroll
            for (int i3 = 0; i3 < 2; ++i3) {
                int n = i2 * 32 + (t >> 3);
                int ch = (t & 7) + i3 * 8;
                bf16x8 v = *(const bf16x8*)(sT + n * 136 + ch * 8);
                *(bf16x8*)(Vt + (size_t)(n0 + n) * M_TOT + m0 + ch * 8) = v;
            }
    }
}

// ---------------------------------------------------------------------------
// Kernel 4: banded attention — r8-passing compute, 1-D grid with XCD swizzle:
// each XCD owns 64 consecutive q-tiles (half a batch), so the sliding K/V
// window stays L2-resident within the XCD (~300 KB active set).
__global__ __launch_bounds__(256) void attn(const unsigned short* __restrict__ Qg,
                                            const unsigned short* __restrict__ Kg,
                                            const unsigned short* __restrict__ Vt,
                                            float* __restrict__ out) {
    __shared__ __align__(16) unsigned short sQ[32 * 520];    // 33,280 B (padded)
    __shared__ __align__(16) unsigned short sKV[32 * 520];   // 33,280 B: K[32][520] | V[512][32]
    __shared__ __align__(16) unsigned short sP[32 * 40];     //  2,560 B (padded)
    __shared__ float lsum[32];

    const int t = threadIdx.x;
    // XCD swizzle: physical p -> logical l = (p&7)*64 + p/8
    const int p = blockIdx.x;
    const int l = (p & 7) * 64 + (p >> 3);
    const int q0 = (l & 127) * 32;       // query offset within batch
    const int b = l >> 7;
    const int bS = b * S_LEN;
    const int w = t >> 6, lane = t & 63;
    const int qd = lane >> 4, l16 = lane & 15;
    const int qh = (w >> 1) * 16, kh = (w & 1) * 16;

    if (t < 32) lsum[t] = 0.f;

    // stage Q tile once: [32][512] bf16, rows padded to 520
    #pragma unroll
    for (int i = 0; i < 8; ++i) {
        int c = i * 256 + t;
        int row = c >> 6, cc = c & 63;
        async_copy16(Qg + (bS + q0 + row) * 512 + cc * 8, sQ + row * 520 + cc * 8);
    }

    f32x4 oacc[16] = {};   // [c4][qt][dt]

    for (int kt = 0; kt < 9; ++kt) {
        int key0 = q0 - HALF_W + kt * 32;
        if (key0 + 32 <= 0 || key0 >= S_LEN) continue;   // block-uniform skip

        // ---- (a) previous V reads done; stage full K tile [32][520-padded]
        __syncthreads();
        #pragma unroll
        for (int i = 0; i < 8; ++i) {
            int c = i * 256 + t;
            int row = c >> 6, cc = c & 63;
            int rowg = key0 + row;
            rowg = (rowg < 0) ? 0 : ((rowg > S_LEN - 1) ? S_LEN - 1 : rowg);
            async_copy16(Kg + (bS + rowg) * 512 + cc * 8, sKV + row * 520 + cc * 8);
        }
        __syncthreads();   // (b) K ready

        // ---- scores: S[32q][32k] = Q . K^T over full D
        f32x4 sacc = {0.f, 0.f, 0.f, 0.f};
        #pragma unroll
        for (int c4 = 0; c4 < 4; ++c4) {
            #pragma unroll
            for (int kc = 0; kc < 4; ++kc) {
                bf16x8 aq = *(const bf16x8*)(sQ + (qh + l16) * 520 + c4 * 128 + kc * 32 + qd * 8);
                bf16x8 bk8 = *(const bf16x8*)(sKV + (kh + l16) * 520 + c4 * 128 + kc * 32 + qd * 8);
                sacc = __builtin_amdgcn_mfma_f32_16x16x32_bf16(aq, bk8, sacc, 0, 0, 0);
            }
        }

        // ---- mask + exp + write P + row sums
        const float scale = 0.04419417382415922f;   // 1/sqrt(512)
        #pragma unroll
        for (int r = 0; r < 4; ++r) {
            int qi = q0 + qh + qd * 4 + r;
            int kj = key0 + kh + l16;
            bool valid = (kj >= 0) && (kj < S_LEN) && (kj >= qi - HALF_W) && (kj <= qi + HALF_W);
            float p2 = valid ? __expf(sacc[r] * scale) : 0.f;
            sP[(qh + qd * 4 + r) * 40 + kh + l16] = f2bf(p2);
            float s = p2;
            s += __shfl_xor(s, 1);
            s += __shfl_xor(s, 2);
            s += __shfl_xor(s, 4);
            s += __shfl_xor(s, 8);
            if (l16 == 0) atomicAdd(&lsum[qh + qd * 4 + r], s);
        }

        // ---- (c) K reads done, sP published; stage FULL V tile [512][32]
        __syncthreads();
        #pragma unroll
        for (int i = 0; i < 8; ++i) {
            int c = i * 256 + t;
            int row = c >> 2, cc = c & 3;
            int kk = key0 + cc * 8;
            int koff = (kk >= 0 && kk + 8 <= S_LEN) ? kk : 0;   // clamped, masked via P=0
            async_copy16(Vt + (size_t)row * M_TOT + bS + koff, sKV + c * 8);
        }
        __syncthreads();   // (d) V ready

        // ---- PV: O[32q][512d] += P . V (no barriers inside)
        #pragma unroll
        for (int c4 = 0; c4 < 4; ++c4) {
            #pragma unroll
            for (int qt = 0; qt < 2; ++qt) {
                bf16x8 ap = *(const bf16x8*)(sP + (qt * 16 + l16) * 40 + qd * 8);
                #pragma unroll
                for (int dt = 0; dt < 2; ++dt) {
                    bf16x8 bv8 = *(const bf16x8*)(sKV + (c4 * 128 + w * 32 + dt * 16 + l16) * 32 + qd * 8);
                    oacc[c4 * 4 + qt * 2 + dt] =
                        __builtin_amdgcn_mfma_f32_16x16x32_bf16(ap, bv8, oacc[c4 * 4 + qt * 2 + dt], 0, 0, 0);
                }
            }
        }
    }

    __syncthreads();   // lsum final
    #pragma unroll
    for (int c4 = 0; c4 < 4; ++c4)
        #pragma unroll
        for (int qt = 0; qt < 2; ++qt)
            #pragma unroll
            for (int dt = 0; dt < 2; ++dt) {
                int dv = c4 * 128 + w * 32 + dt * 16 + l16;
                #pragma unroll
                for (int r = 0; r < 4; ++r) {
                    int q = qt * 16 + qd * 4 + r;
                    out[(size_t)(bS + q0 + q) * 512 + dv] = oacc[c4 * 4 + qt * 2 + dt][r] / lsum[q];
                }
            }
}

// ---------------------------------------------------------------------------
extern "C" void kernel_launch(void* const* d_in, const int* in_sizes, int n_in,
                              void* d_out, int out_size, void* d_ws, size_t ws_size,
                              hipStream_t stream) {
    const float* x  = (const float*)d_in[0];
    const float* Wq = (const float*)d_in[1];
    const float* bq = (const float*)d_in[2];
    const float* Wk = (const float*)d_in[3];
    const float* bk = (const float*)d_in[4];
    const float* Wv = (const float*)d_in[5];
    const float* bv = (const float*)d_in[6];
    float* out = (float*)d_out;

    char* ws = (char*)d_ws;
    unsigned short* xb = (unsigned short*)(ws);                    // 16 MB
    unsigned short* Wt = (unsigned short*)(ws + 16777216);         // 1.5 MB
    unsigned short* Qb = (unsigned short*)(ws + 18350080);         // 16 MB
    unsigned short* Kb = (unsigned short*)(ws + 35127296);         // 16 MB
    unsigned short* Vt = (unsigned short*)(ws + 51904512);         // 16 MB, [512][16384]

    convert_x<<<8192, 256, 0, stream>>>(x, xb);
    convert_w<<<dim3(8, 8, 3), 256, 0, stream>>>(Wq, Wk, Wv, Wt);
    qkv_gemm<<<1536, 256, 0, stream>>>(xb, Wt, bq, bk, bv, Qb, Kb, Vt);
    attn<<<512, 256, 0, stream>>>(Qb, Kb, Vt, out);
}

// Round 10
// 167.210 us; speedup vs baseline: 1.3808x; 1.0501x over previous
//
#include <hip/hip_runtime.h>
#include <hip/hip_bf16.h>

// Problem constants
#define S_LEN   4096
#define D_MOD   512
#define BATCH   4
#define HALF_W  128
#define M_TOT   (BATCH * S_LEN)   // 16384

typedef __attribute__((ext_vector_type(8))) short bf16x8;
typedef __attribute__((ext_vector_type(4))) float f32x4;

__device__ __forceinline__ unsigned short f2bf(float f) {
    // round-to-nearest-even bf16 (values are finite here)
    unsigned int u = __float_as_uint(f);
    unsigned int r = (u + 0x7fffu + ((u >> 16) & 1u)) >> 16;
    return (unsigned short)r;
}

__device__ __forceinline__ void async_copy16(const void* g, void* l) {
    __builtin_amdgcn_global_load_lds(
        (const __attribute__((address_space(1))) void*)g,
        (__attribute__((address_space(3))) void*)l, 16, 0, 0);
}

// ---------------------------------------------------------------------------
// Kernel 1: fused converts. Blocks [0,8192): x fp32 -> bf16 (r1-verbatim body).
// Blocks [8192,8384): W[k][n] -> Wt[n][k] bf16 via LDS transpose (r7 body).
__global__ __launch_bounds__(256) void convert_xw(const float* __restrict__ x,
                                                  const float* __restrict__ Wq,
                                                  const float* __restrict__ Wk,
                                                  const float* __restrict__ Wv,
                                                  unsigned short* __restrict__ xb,
                                                  unsigned short* __restrict__ Wt) {
    __shared__ float sT[64][65];
    const int t = threadIdx.x;
    const int bid = blockIdx.x;
    if (bid < 8192) {
        int i = (bid * 256 + t) * 4;
        float4 v = *(const float4*)(x + i);
        ushort4 o;
        o.x = f2bf(v.x); o.y = f2bf(v.y); o.z = f2bf(v.z); o.w = f2bf(v.w);
        *(ushort4*)(xb + i) = o;
        return;
    }
    const int j = bid - 8192;            // 0..191
    const int w = j >> 6;                // weight select (64 tiles each)
    const int rj = j & 63;
    const float* W = (w == 0) ? Wq : ((w == 1) ? Wk : Wv);
    const int n0 = (rj & 7) * 64, k0 = (rj >> 3) * 64;
    const int r = t >> 4, c4 = (t & 15) * 4;
    #pragma unroll
    for (int i = 0; i < 4; ++i) {
        float4 v = *(const float4*)(W + (size_t)(k0 + r + i * 16) * 512 + n0 + c4);
        sT[c4 + 0][r + i * 16] = v.x;
        sT[c4 + 1][r + i * 16] = v.y;
        sT[c4 + 2][r + i * 16] = v.z;
        sT[c4 + 3][r + i * 16] = v.w;
    }
    __syncthreads();
    #pragma unroll
    for (int i = 0; i < 4; ++i) {
        int rr = (t >> 4) + i * 16;   // n-local
        ushort4 o;
        o.x = f2bf(sT[rr][c4 + 0]);
        o.y = f2bf(sT[rr][c4 + 1]);
        o.z = f2bf(sT[rr][c4 + 2]);
        o.w = f2bf(sT[rr][c4 + 3]);
        *(ushort4*)(Wt + (size_t)w * 262144 + (size_t)(n0 + rr) * 512 + k0 + c4) = o;
    }
}

// ---------------------------------------------------------------------------
// Kernel 2: fused QKV GEMM (r9-passing structure + XCD swizzle) with
// bank-conflict-free LDS: the global SOURCE chunk within each 128 B row
// segment is permuted (g = cc ^ (row&7)); the LDS destination stays lane-
// linear (async rule respected), and fragment reads XOR their chunk index
// by (row&7) -> 8 distinct 4-bank groups per read = 2-way = free.
__global__ __launch_bounds__(256) void qkv_gemm(
    const unsigned short* __restrict__ xb, const unsigned short* __restrict__ Wt,
    const float* __restrict__ bq, const float* __restrict__ bk, const float* __restrict__ bv,
    unsigned short* __restrict__ Qo, unsigned short* __restrict__ Ko,
    unsigned short* __restrict__ Vt) {
    __shared__ __align__(16) char gsmem[34816];
    unsigned short* sA = (unsigned short*)gsmem;            // [128][64], chunk-swizzled
    unsigned short* sB = (unsigned short*)(gsmem + 16384);  // [128][64], chunk-swizzled
    unsigned short* sT = (unsigned short*)gsmem;            // [128][136] epilogue

    const int t = threadIdx.x;
    // XCD swizzle: physical p -> xcd = p&7; each XCD gets 192 contiguous
    // logical blocks = 16 m-tiles * 12 (z,n) combos.
    const int p = blockIdx.x;
    const int l = (p & 7) * 192 + (p >> 3);
    const int mi = l / 12;
    const int rzn = l - mi * 12;
    const int wsel = rzn >> 2;
    const int ni = rzn & 3;
    const int m0 = mi * 128;
    const int n0 = ni * 128;
    const unsigned short* Wb = Wt + (size_t)wsel * 262144;

    const int w = t >> 6, lane = t & 63;
    const int wm = (w & 1) * 64, wn = (w >> 1) * 64;
    const int qd = lane >> 4, l16 = lane & 15;

    f32x4 acc[4][4] = {};

    for (int k0 = 0; k0 < 512; k0 += 64) {
        __syncthreads();
        #pragma unroll
        for (int i = 0; i < 4; ++i) {
            int c = i * 256 + t;
            int row = c >> 3, cc = c & 7;
            int g = cc ^ (row & 7);                       // source-chunk permute
            async_copy16(xb + (size_t)(m0 + row) * 512 + k0 + g * 8, sA + c * 8);
            async_copy16(Wb + (size_t)(n0 + row) * 512 + k0 + g * 8, sB + c * 8);
        }
        __syncthreads();
        #pragma unroll
        for (int ks = 0; ks < 2; ++ks) {
            bf16x8 af[4], bfr[4];
            #pragma unroll
            for (int i = 0; i < 4; ++i) {
                int row = wm + i * 16 + l16;
                int ch = (ks * 4 + qd) ^ (row & 7);       // logical chunk ks*4+qd
                af[i] = *(const bf16x8*)(sA + row * 64 + ch * 8);
            }
            #pragma unroll
            for (int j = 0; j < 4; ++j) {
                int row = wn + j * 16 + l16;
                int ch = (ks * 4 + qd) ^ (row & 7);
                bfr[j] = *(const bf16x8*)(sB + row * 64 + ch * 8);
            }
            #pragma unroll
            for (int i = 0; i < 4; ++i)
                #pragma unroll
                for (int j = 0; j < 4; ++j)
                    acc[i][j] = __builtin_amdgcn_mfma_f32_16x16x32_bf16(af[i], bfr[j], acc[i][j], 0, 0, 0);
        }
    }

    const float* bias = (wsel == 0) ? bq : ((wsel == 1) ? bk : bv);
    __syncthreads();   // done reading sA/sB; sT aliases them

    if (wsel < 2) {
        #pragma unroll
        for (int j = 0; j < 4; ++j) {
            int n = wn + j * 16 + l16;
            float bj = bias[n0 + n];
            #pragma unroll
            for (int i = 0; i < 4; ++i) {
                int mb = wm + i * 16 + qd * 4;
                #pragma unroll
                for (int r = 0; r < 4; ++r)
                    sT[(mb + r) * 136 + n] = f2bf(acc[i][j][r] + bj);
            }
        }
        __syncthreads();
        unsigned short* Og = (wsel == 0) ? Qo : Ko;
        #pragma unroll
        for (int i2 = 0; i2 < 4; ++i2)
            #pragma unroll
            for (int i3 = 0; i3 < 2; ++i3) {
                int m = i2 * 32 + (t >> 3);
                int ch = (t & 7) + i3 * 8;
                bf16x8 v = *(const bf16x8*)(sT + m * 136 + ch * 8);
                *(bf16x8*)(Og + (size_t)(m0 + m) * 512 + n0 + ch * 8) = v;
            }
    } else {
        #pragma unroll
        for (int j = 0; j < 4; ++j) {
            int n = wn + j * 16 + l16;
            float bj = bias[n0 + n];
            #pragma unroll
            for (int i = 0; i < 4; ++i) {
                int mb = wm + i * 16 + qd * 4;
                #pragma unroll
                for (int r = 0; r < 4; ++r)
                    sT[n * 136 + mb + r] = f2bf(acc[i][j][r] + bj);
            }
        }
        __syncthreads();
        #pragma unroll
        for (int i2 = 0; i2 < 4; ++i2)
            #pragma unroll
            for (int i3 = 0; i3 < 2; ++i3) {
                int n = i2 * 32 + (t >> 3);
                int ch = (t & 7) + i3 * 8;
                bf16x8 v = *(const bf16x8*)(sT + n * 136 + ch * 8);
                *(bf16x8*)(Vt + (size_t)(n0 + n) * M_TOT + m0 + ch * 8) = v;
            }
    }
}

// ---------------------------------------------------------------------------
// Kernel 3: banded attention — r9-passing version, byte-identical.
__global__ __launch_bounds__(256) void attn(const unsigned short* __restrict__ Qg,
                                            const unsigned short* __restrict__ Kg,
                                            const unsigned short* __restrict__ Vt,
                                            float* __restrict__ out) {
    __shared__ __align__(16) unsigned short sQ[32 * 520];    // 33,280 B (padded)
    __shared__ __align__(16) unsigned short sKV[32 * 520];   // 33,280 B: K[32][520] | V[512][32]
    __shared__ __align__(16) unsigned short sP[32 * 40];     //  2,560 B (padded)
    __shared__ float lsum[32];

    const int t = threadIdx.x;
    // XCD swizzle: physical p -> logical l = (p&7)*64 + p/8
    const int p = blockIdx.x;
    const int l = (p & 7) * 64 + (p >> 3);
    const int q0 = (l & 127) * 32;       // query offset within batch
    const int b = l >> 7;
    const int bS = b * S_LEN;
    const int w = t >> 6, lane = t & 63;
    const int qd = lane >> 4, l16 = lane & 15;
    const int qh = (w >> 1) * 16, kh = (w & 1) * 16;

    if (t < 32) lsum[t] = 0.f;

    // stage Q tile once: [32][512] bf16, rows padded to 520
    #pragma unroll
    for (int i = 0; i < 8; ++i) {
        int c = i * 256 + t;
        int row = c >> 6, cc = c & 63;
        async_copy16(Qg + (bS + q0 + row) * 512 + cc * 8, sQ + row * 520 + cc * 8);
    }

    f32x4 oacc[16] = {};   // [c4][qt][dt]

    for (int kt = 0; kt < 9; ++kt) {
        int key0 = q0 - HALF_W + kt * 32;
        if (key0 + 32 <= 0 || key0 >= S_LEN) continue;   // block-uniform skip

        // ---- (a) previous V reads done; stage full K tile [32][520-padded]
        __syncthreads();
        #pragma unroll
        for (int i = 0; i < 8; ++i) {
            int c = i * 256 + t;
            int row = c >> 6, cc = c & 63;
            int rowg = key0 + row;
            rowg = (rowg < 0) ? 0 : ((rowg > S_LEN - 1) ? S_LEN - 1 : rowg);
            async_copy16(Kg + (bS + rowg) * 512 + cc * 8, sKV + row * 520 + cc * 8);
        }
        __syncthreads();   // (b) K ready

        // ---- scores: S[32q][32k] = Q . K^T over full D
        f32x4 sacc = {0.f, 0.f, 0.f, 0.f};
        #pragma unroll
        for (int c4 = 0; c4 < 4; ++c4) {
            #pragma unroll
            for (int kc = 0; kc < 4; ++kc) {
                bf16x8 aq = *(const bf16x8*)(sQ + (qh + l16) * 520 + c4 * 128 + kc * 32 + qd * 8);
                bf16x8 bk8 = *(const bf16x8*)(sKV + (kh + l16) * 520 + c4 * 128 + kc * 32 + qd * 8);
                sacc = __builtin_amdgcn_mfma_f32_16x16x32_bf16(aq, bk8, sacc, 0, 0, 0);
            }
        }

        // ---- mask + exp + write P + row sums
        const float scale = 0.04419417382415922f;   // 1/sqrt(512)
        #pragma unroll
        for (int r = 0; r < 4; ++r) {
            int qi = q0 + qh + qd * 4 + r;
            int kj = key0 + kh + l16;
            bool valid = (kj >= 0) && (kj < S_LEN) && (kj >= qi - HALF_W) && (kj <= qi + HALF_W);
            float p2 = valid ? __expf(sacc[r] * scale) : 0.f;
            sP[(qh + qd * 4 + r) * 40 + kh + l16] = f2bf(p2);
            float s = p2;
            s += __shfl_xor(s, 1);
            s += __shfl_xor(s, 2);
            s += __shfl_xor(s, 4);
            s += __shfl_xor(s, 8);
            if (l16 == 0) atomicAdd(&lsum[qh + qd * 4 + r], s);
        }

        // ---- (c) K reads done, sP published; stage FULL V tile [512][32]
        __syncthreads();
        #pragma unroll
        for (int i = 0; i < 8; ++i) {
            int c = i * 256 + t;
            int row = c >> 2, cc = c & 3;
            int kk = key0 + cc * 8;
            int koff = (kk >= 0 && kk + 8 <= S_LEN) ? kk : 0;   // clamped, masked via P=0
            async_copy16(Vt + (size_t)row * M_TOT + bS + koff, sKV + c * 8);
        }
        __syncthreads();   // (d) V ready

        // ---- PV: O[32q][512d] += P . V (no barriers inside)
        #pragma unroll
        for (int c4 = 0; c4 < 4; ++c4) {
            #pragma unroll
            for (int qt = 0; qt < 2; ++qt) {
                bf16x8 ap = *(const bf16x8*)(sP + (qt * 16 + l16) * 40 + qd * 8);
                #pragma unroll
                for (int dt = 0; dt < 2; ++dt) {
                    bf16x8 bv8 = *(const bf16x8*)(sKV + (c4 * 128 + w * 32 + dt * 16 + l16) * 32 + qd * 8);
                    oacc[c4 * 4 + qt * 2 + dt] =
                        __builtin_amdgcn_mfma_f32_16x16x32_bf16(ap, bv8, oacc[c4 * 4 + qt * 2 + dt], 0, 0, 0);
                }
            }
        }
    }

    __syncthreads();   // lsum final
    #pragma unroll
    for (int c4 = 0; c4 < 4; ++c4)
        #pragma unroll
        for (int qt = 0; qt < 2; ++qt)
            #pragma unroll
            for (int dt = 0; dt < 2; ++dt) {
                int dv = c4 * 128 + w * 32 + dt * 16 + l16;
                #pragma unroll
                for (int r = 0; r < 4; ++r) {
                    int q = qt * 16 + qd * 4 + r;
                    out[(size_t)(bS + q0 + q) * 512 + dv] = oacc[c4 * 4 + qt * 2 + dt][r] / lsum[q];
                }
            }
}

// ---------------------------------------------------------------------------
extern "C" void kernel_launch(void* const* d_in, const int* in_sizes, int n_in,
                              void* d_out, int out_size, void* d_ws, size_t ws_size,
                              hipStream_t stream) {
    const float* x  = (const float*)d_in[0];
    const float* Wq = (const float*)d_in[1];
    const float* bq = (const float*)d_in[2];
    const float* Wk = (const float*)d_in[3];
    const float* bk = (const float*)d_in[4];
    const float* Wv = (const float*)d_in[5];
    const float* bv = (const float*)d_in[6];
    float* out = (float*)d_out;

    char* ws = (char*)d_ws;
    unsigned short* xb = (unsigned short*)(ws);                    // 16 MB
    unsigned short* Wt = (unsigned short*)(ws + 16777216);         // 1.5 MB
    unsigned short* Qb = (unsigned short*)(ws + 18350080);         // 16 MB
    unsigned short* Kb = (unsigned short*)(ws + 35127296);         // 16 MB
    unsigned short* Vt = (unsigned short*)(ws + 51904512);         // 16 MB, [512][16384]

    convert_xw<<<8384, 256, 0, stream>>>(x, Wq, Wk, Wv, xb, Wt);
    qkv_gemm<<<1536, 256, 0, stream>>>(xb, Wt, bq, bk, bv, Qb, Kb, Vt);
    attn<<<512, 256, 0, stream>>>(Qb, Kb, Vt, out);
}